// Round 16
// baseline (507.709 us; speedup 1.0000x reference)
//
#include <hip/hip_runtime.h>

#define NB   32
#define CIN  256
#define CM   64
#define HWSZ 4096
#define OC   384
#define KTOT 192

typedef __attribute__((ext_vector_type(8))) short bf16x8;
typedef __attribute__((ext_vector_type(4))) float f32x4;

static __device__ __forceinline__ unsigned short f2bf(float v) {
    union { float f; unsigned u; } a; a.f = v;
    unsigned r = a.u + 0x7fffu + ((a.u >> 16) & 1u);
    return (unsigned short)(r >> 16);
}
static __device__ __forceinline__ float bf2f(unsigned short u) {
    union { unsigned u; float f; } a; a.u = ((unsigned)u) << 16;
    return a.f;
}

// ---------- precompute Wb bf16 [384 oc][192 k], bt[384], cwb bf16 [64 ch][256 k], zero xm ----------
__global__ void kw_pre(const float* __restrict__ fuse_w, const float* __restrict__ fuse_b,
                       const float* __restrict__ fc_w, const float* __restrict__ fc_b,
                       const float* __restrict__ conv_w,
                       unsigned short* __restrict__ Wb, float* __restrict__ bt,
                       unsigned short* __restrict__ cwb, float* __restrict__ xm) {
    int k = blockIdx.x;      // 0..192 ; 192 = bias block + cwb convert + xm zero
    int o = threadIdx.x;     // 0..383
    if (k == KTOT) {
        __shared__ float fb[128];
        if (o < 128) fb[o] = fuse_b[o];
        __syncthreads();
        float s = fc_b[o];
        #pragma unroll 4
        for (int q = 0; q < 384; ++q) s += fc_w[o * 384 + q] * fb[q & 127];
        bt[o] = s;
        for (int idx = o; idx < CM * CIN; idx += 384) cwb[idx] = f2bf(conv_w[idx]);
        for (int idx = o; idx < NB * CIN; idx += 384) xm[idx] = 0.f;
        return;
    }
    int i = k >> 6, c = k & 63;
    __shared__ float fw[128];
    if (o < 128) fw[o] = fuse_w[o * 64 + c];
    __syncthreads();
    float s = 0.f;
    #pragma unroll 8
    for (int j = 0; j < 128; ++j) s += fc_w[o * 384 + i * 128 + j] * fw[j];
    Wb[o * KTOT + k] = f2bf(s);
}

// ---------- k3: f_t[n][pix][64] = relu(conv_w @ x + b) via MFMA; also accumulates channel sums ----------
// grid (16 ptiles, 32 n), block 256 (4 waves). Tile: 256 pix (M) x 64 ch (N), K=256.
// Mean fused: per-wave shuffle partial sums -> LDS atomics -> one global atomic per cin per block.
// XCD swizzle: XCD j handles n in [4j,4j+4) (matches k45's mapping for cross-kernel f_t L2 reuse).
// x loads NON-TEMPORAL (read-once stream) -- measured R13: NT package = -12.5us vs non-NT baseline.
__global__ void __launch_bounds__(256) k3_fconv(const float* __restrict__ x,
                                                const unsigned short* __restrict__ cwb,
                                                const float* __restrict__ conv_b,
                                                unsigned short* __restrict__ f_t,
                                                float* __restrict__ xm) {
    __shared__ unsigned short Ab[256 * 40];   // x-tile [pix][32k + 8 pad]
    __shared__ unsigned short Bb[64 * 264];   // cwb [ch][256k + 8 pad]
    __shared__ float sm[CIN];                 // per-block channel sums
    int orig = blockIdx.y * 16 + blockIdx.x;          // 512 blocks, 512%8==0 -> bijective swizzle
    int swz = (orig & 7) * 64 + (orig >> 3);
    int pt = swz & 15, n = swz >> 4;
    int p0 = pt * 256;
    int t = threadIdx.x;
    int lane = t & 63;
    int wv = t >> 6;
    int q = lane >> 4, m16 = lane & 15;

    sm[t] = 0.f;   // 256 threads == CIN

    #pragma unroll
    for (int i = 0; i < 8; ++i) {
        int id = t + i * 256;
        int row = id >> 5, seg = id & 31;
        bf16x8 v = *(const bf16x8*)(cwb + row * CIN + seg * 8);
        *(bf16x8*)(&Bb[row * 264 + seg * 8]) = v;
    }

    f32x4 acc[4][4];
    #pragma unroll
    for (int mt = 0; mt < 4; ++mt)
        #pragma unroll
        for (int nt = 0; nt < 4; ++nt)
            #pragma unroll
            for (int r = 0; r < 4; ++r) acc[mt][nt][r] = 0.f;

    const float* xn = x + (size_t)n * CIN * HWSZ;

    for (int kc = 0; kc < 8; ++kc) {
        __syncthreads();
        #pragma unroll
        for (int i = 0; i < 2; ++i) {
            int id = t + i * 256;
            int kq = id & 7, pg = id >> 3;       // kq: 4-cin group, pg: 4-pixel group
            int cin0 = kc * 32 + kq * 4;
            const float* xp = xn + (size_t)cin0 * HWSZ + p0 + pg * 4;
            f32x4 r0 = __builtin_nontemporal_load((const f32x4*)(xp));
            f32x4 r1 = __builtin_nontemporal_load((const f32x4*)(xp + HWSZ));
            f32x4 r2 = __builtin_nontemporal_load((const f32x4*)(xp + 2 * HWSZ));
            f32x4 r3 = __builtin_nontemporal_load((const f32x4*)(xp + 3 * HWSZ));
            uint2 w;
            w.x = (unsigned)f2bf(r0.x) | ((unsigned)f2bf(r1.x) << 16);
            w.y = (unsigned)f2bf(r2.x) | ((unsigned)f2bf(r3.x) << 16);
            *(uint2*)(&Ab[(pg * 4 + 0) * 40 + kq * 4]) = w;
            w.x = (unsigned)f2bf(r0.y) | ((unsigned)f2bf(r1.y) << 16);
            w.y = (unsigned)f2bf(r2.y) | ((unsigned)f2bf(r3.y) << 16);
            *(uint2*)(&Ab[(pg * 4 + 1) * 40 + kq * 4]) = w;
            w.x = (unsigned)f2bf(r0.z) | ((unsigned)f2bf(r1.z) << 16);
            w.y = (unsigned)f2bf(r2.z) | ((unsigned)f2bf(r3.z) << 16);
            *(uint2*)(&Ab[(pg * 4 + 2) * 40 + kq * 4]) = w;
            w.x = (unsigned)f2bf(r0.w) | ((unsigned)f2bf(r1.w) << 16);
            w.y = (unsigned)f2bf(r2.w) | ((unsigned)f2bf(r3.w) << 16);
            *(uint2*)(&Ab[(pg * 4 + 3) * 40 + kq * 4]) = w;
            // fused mean: per-lane pixel sums for 4 cins, xor-reduce over pg bits, LDS atomic per lane<8
            float s0 = r0.x + r0.y + r0.z + r0.w;
            float s1 = r1.x + r1.y + r1.z + r1.w;
            float s2 = r2.x + r2.y + r2.z + r2.w;
            float s3 = r3.x + r3.y + r3.z + r3.w;
            #pragma unroll
            for (int off = 8; off < 64; off <<= 1) {
                s0 += __shfl_xor(s0, off);
                s1 += __shfl_xor(s1, off);
                s2 += __shfl_xor(s2, off);
                s3 += __shfl_xor(s3, off);
            }
            if (lane < 8) {
                float* sp = &sm[kc * 32 + lane * 4];
                atomicAdd(sp + 0, s0);
                atomicAdd(sp + 1, s1);
                atomicAdd(sp + 2, s2);
                atomicAdd(sp + 3, s3);
            }
        }
        __syncthreads();
        bf16x8 af[4], bfr[4];
        #pragma unroll
        for (int mt = 0; mt < 4; ++mt)
            af[mt] = *(const bf16x8*)(&Ab[(wv * 64 + mt * 16 + m16) * 40 + q * 8]);
        #pragma unroll
        for (int nt = 0; nt < 4; ++nt)
            bfr[nt] = *(const bf16x8*)(&Bb[(nt * 16 + m16) * 264 + kc * 32 + q * 8]);
        #pragma unroll
        for (int mt = 0; mt < 4; ++mt)
            #pragma unroll
            for (int nt = 0; nt < 4; ++nt)
                acc[mt][nt] = __builtin_amdgcn_mfma_f32_16x16x32_bf16(af[mt], bfr[nt], acc[mt][nt], 0, 0, 0);
    }

    // per-block channel sums -> one global atomic per cin (last in-loop barrier guarantees sm complete)
    atomicAdd(xm + n * CIN + t, sm[t]);

    unsigned short* fo = f_t + (size_t)n * HWSZ * CM;
    #pragma unroll
    for (int nt = 0; nt < 4; ++nt) {
        int ch = nt * 16 + m16;
        float b = conv_b[ch];
        #pragma unroll
        for (int mt = 0; mt < 4; ++mt) {
            int pixb = p0 + wv * 64 + mt * 16 + q * 4;
            #pragma unroll
            for (int r = 0; r < 4; ++r) {
                float v = fmaxf(acc[mt][nt][r] + b, 0.f);
                fo[(size_t)(pixb + r) * CM + ch] = f2bf(v);
            }
        }
    }
}

// ---------- k45 (R16 LDS-diet): g+taps inline -> depthwise DIRECT-FROM-L2 -> MFMA GEMM (64-oc chunks) ----------
// grid (32 tiles, 32 n), block 512 (8 waves). Tile = 4 rows x 32 cols of pixels (full 128B out lines).
// NO halo LDS staging: per-XCD f_t working set (4 x 524 KB via the n<->XCD swizzle) L2-fits, so the
// depthwise window reads go straight to L2 (catalog mistake #7: don't stage what L2-fits). Thread map
// ch=t&63: every window address is WAVE-UNIFORM (scalar bounds checks, one coalesced 128B line per tap);
// taps drop to 43 VGPRs. LDS 120.8 -> 77.3 KB -> 2 blocks/CU (launch_bounds(512,4), VGPR<=128):
// co-resident blocks overlap depthwise VALU / Wb staging / MFMA / stores. Unlike R7's retile (which
// regressed by ADDING staging work for occupancy), this removes work AND gains occupancy.
// [R13: NT loads/stores = -12.5us, kept. R15: k2 fusion flat, kept.]
__global__ void __launch_bounds__(512, 4) k45_dwgemm(const unsigned short* __restrict__ f_t,
                                                     const float* __restrict__ xm,
                                                     const float* __restrict__ conv_w,
                                                     const float* __restrict__ conv_b,
                                                     const float* ck_w, const float* ck_b,
                                                     const float* ck2_w, const float* ck2_b,
                                                     const float* ckd4_w, const float* ckd4_b,
                                                     const float* kern_w, const float* kern_b,
                                                     const float* kern2_w, const float* kern2_b,
                                                     const float* kernd4_w, const float* kernd4_b,
                                                     const unsigned short* __restrict__ Wb,
                                                     const float* __restrict__ bt,
                                                     float* __restrict__ out) {
    __shared__ unsigned short ot[128 * 200];  // [128 pix][192k + 8 pad]
    __shared__ unsigned short wbs[64 * 200];  // Wb chunk [64oc][192k + 8 pad]
    __shared__ float bts[64];
    __shared__ float g_sm[CM];                // g = relu(mean @ conv_w^T + b), computed by wave 0
    int orig = blockIdx.y * 32 + blockIdx.x;          // 1024 blocks, 1024%8==0 -> bijective swizzle
    int swz = (orig & 7) * 128 + (orig >> 3);
    int tile = swz & 31, n = swz >> 5;
    int r0 = (tile >> 1) * 4, c0 = (tile & 1) * 32;
    int t = threadIdx.x;
    int lane = t & 63, wv = t >> 6;

    // --- fused k2: wave 0 computes g[c] (xm row wave-uniform -> broadcast; conv_w row per lane) ---
    if (t < CM) {
        const f32x4* xr = (const f32x4*)(xm + (size_t)n * CIN);
        const f32x4* wr = (const f32x4*)(conv_w + t * CIN);
        float a = 0.f;
        #pragma unroll 8
        for (int i = 0; i < CIN / 4; ++i) {
            f32x4 xv = xr[i], wvv = wr[i];
            a = fmaf(xv.x, wvv.x, a); a = fmaf(xv.y, wvv.y, a);
            a = fmaf(xv.z, wvv.z, a); a = fmaf(xv.w, wvv.w, a);
        }
        g_sm[t] = fmaxf(conv_b[t] + a * (1.0f / 4096.0f), 0.f);
    }
    __syncthreads();

    // --- taps in registers (one channel per lane; exact k2 expressions) ---
    int ch = t & 63;          // channel
    int pgw = t >> 6;         // wave id == pixel subgroup
    float gch = g_sm[ch];
    float t1[25], t2[9], t3[9];
    {
        float sw = ck_w[0], sb = ck_b[0];
        #pragma unroll
        for (int i = 0; i < 25; ++i) t1[i] = sw * (gch * kern_w[i] + kern_b[i]) + sb;
        sw = ck2_w[0]; sb = ck2_b[0];
        #pragma unroll
        for (int i = 0; i < 9; ++i) t2[i] = sw * (gch * kern2_w[i] + kern2_b[i]) + sb;
        sw = ckd4_w[0]; sb = ckd4_b[0];
        #pragma unroll
        for (int i = 0; i < 9; ++i) t3[i] = sw * (gch * kernd4_w[i] + kernd4_b[i]) + sb;
    }

    // --- depthwise direct from L2-hot f_t into ot (d2 subset of d1 window; d4 center == d1 center) ---
    const unsigned short* fn = f_t + (size_t)n * HWSZ * CM;
    for (int pass = 0; pass < 16; ++pass) {
        int pli = pgw + pass * 8;            // 0..127 (wave-uniform)
        int prb = r0 + (pli >> 5), pcb = c0 + (pli & 31);
        float s1 = 0.f, s2 = 0.f, s3 = 0.f;
        #pragma unroll
        for (int ky = 0; ky < 5; ++ky)
            #pragma unroll
            for (int kx = 0; kx < 5; ++kx) {
                int pr = prb + ky - 2, pc = pcb + kx - 2;
                float fe = 0.f;
                if ((unsigned)pr < 64u && (unsigned)pc < 64u)
                    fe = bf2f(fn[(size_t)(pr * 64 + pc) * CM + ch]);
                s1 = fmaf(t1[ky * 5 + kx], fe, s1);
                if (((ky & 1) | (kx & 1)) == 0)             // d2 tap
                    s2 = fmaf(t2[(ky >> 1) * 3 + (kx >> 1)], fe, s2);
                if (ky == 2 && kx == 2)                     // d4 center
                    s3 = fmaf(t3[4], fe, s3);
            }
        #pragma unroll
        for (int ky = 0; ky < 3; ++ky)
            #pragma unroll
            for (int kx = 0; kx < 3; ++kx) {
                if (ky == 1 && kx == 1) continue;           // center done
                int pr = prb + ky * 4 - 4, pc = pcb + kx * 4 - 4;
                float fe = 0.f;
                if ((unsigned)pr < 64u && (unsigned)pc < 64u)
                    fe = bf2f(fn[(size_t)(pr * 64 + pc) * CM + ch]);
                s3 = fmaf(t3[ky * 3 + kx], fe, s3);
            }
        unsigned short* ob = &ot[pli * 200];
        ob[ch]       = f2bf(s1);
        ob[64 + ch]  = f2bf(s2);
        ob[128 + ch] = f2bf(s3);
    }

    // --- phase 2: GEMM 384oc x 128pix, K=192, in 6 chunks of 64 oc ---
    int wrow = t >> 3, wqk = t & 7;          // staging: 8 thr/row, 24 shorts each
    int wm = wv & 1, wn = wv >> 1;           // wave -> (oc-half, pix-quarter)
    int q = lane >> 4, m16 = lane & 15;
    float* outn0 = out + (size_t)n * OC * HWSZ;
    for (int ocg = 0; ocg < 6; ++ocg) {
        __syncthreads();
        if (t < 64) bts[t] = bt[ocg * 64 + t];
        #pragma unroll
        for (int j = 0; j < 3; ++j) {
            bf16x8 v = *(const bf16x8*)(Wb + (size_t)(ocg * 64 + wrow) * KTOT + wqk * 24 + j * 8);
            *(bf16x8*)(&wbs[wrow * 200 + wqk * 24 + j * 8]) = v;
        }
        __syncthreads();
        f32x4 acc[2][2];
        #pragma unroll
        for (int mt = 0; mt < 2; ++mt)
            #pragma unroll
            for (int nt = 0; nt < 2; ++nt)
                #pragma unroll
                for (int r = 0; r < 4; ++r) acc[mt][nt][r] = 0.f;
        #pragma unroll
        for (int ks = 0; ks < 6; ++ks) {
            bf16x8 af[2], bfr[2];
            #pragma unroll
            for (int mt = 0; mt < 2; ++mt)
                af[mt] = *(const bf16x8*)(&wbs[(wm * 32 + mt * 16 + m16) * 200 + ks * 32 + q * 8]);
            #pragma unroll
            for (int nt = 0; nt < 2; ++nt)
                bfr[nt] = *(const bf16x8*)(&ot[(wn * 32 + nt * 16 + m16) * 200 + ks * 32 + q * 8]);
            #pragma unroll
            for (int mt = 0; mt < 2; ++mt)
                #pragma unroll
                for (int nt = 0; nt < 2; ++nt)
                    acc[mt][nt] = __builtin_amdgcn_mfma_f32_16x16x32_bf16(af[mt], bfr[nt], acc[mt][nt], 0, 0, 0);
        }
        float* outn = outn0 + (size_t)(ocg * 64) * HWSZ;
        #pragma unroll
        for (int mt = 0; mt < 2; ++mt) {
            #pragma unroll
            for (int r = 0; r < 4; ++r) {
                int ocl = wm * 32 + mt * 16 + q * 4 + r;
                float b = bts[ocl];
                #pragma unroll
                for (int nt = 0; nt < 2; ++nt) {
                    int pl = wn * 32 + nt * 16 + m16;
                    int pr = pl >> 5, pc = pl & 31;
                    __builtin_nontemporal_store(acc[mt][nt][r] + b,
                        &outn[(size_t)ocl * HWSZ + (r0 + pr) * 64 + c0 + pc]);
                }
            }
        }
    }
}

extern "C" void kernel_launch(void* const* d_in, const int* in_sizes, int n_in,
                              void* d_out, int out_size, void* d_ws, size_t ws_size,
                              hipStream_t stream) {
    const float* x       = (const float*)d_in[0];
    const float* conv_w  = (const float*)d_in[1];
    const float* conv_b  = (const float*)d_in[2];
    const float* ck_w    = (const float*)d_in[3];
    const float* ck_b    = (const float*)d_in[4];
    const float* ck2_w   = (const float*)d_in[5];
    const float* ck2_b   = (const float*)d_in[6];
    const float* ckd4_w  = (const float*)d_in[7];
    const float* ckd4_b  = (const float*)d_in[8];
    const float* kern_w  = (const float*)d_in[9];
    const float* kern_b  = (const float*)d_in[10];
    const float* kern2_w = (const float*)d_in[11];
    const float* kern2_b = (const float*)d_in[12];
    const float* kernd4_w= (const float*)d_in[13];
    const float* kernd4_b= (const float*)d_in[14];
    const float* fuse_w  = (const float*)d_in[15];
    const float* fuse_b  = (const float*)d_in[16];
    const float* fc_w    = (const float*)d_in[17];
    const float* fc_b    = (const float*)d_in[18];
    float* out = (float*)d_out;

    char* ws = (char*)d_ws;
    float* xm             = (float*)(ws + 0);                  // 32 KB (sums, zeroed by kw_pre)
    float* bt             = (float*)(ws + 385024);             // 1,536 B
    unsigned short* Wb    = (unsigned short*)(ws + 386560);    // 147,456 B
    unsigned short* cwb   = (unsigned short*)(ws + 534016);    // 32,768 B
    unsigned short* f_t   = (unsigned short*)(ws + 566784);    // 16.78 MB -> ends ~17.3 MB

    kw_pre<<<dim3(193), dim3(384), 0, stream>>>(fuse_w, fuse_b, fc_w, fc_b, conv_w, Wb, bt, cwb, xm);
    k3_fconv<<<dim3(16, NB), dim3(256), 0, stream>>>(x, cwb, conv_b, f_t, xm);
    k45_dwgemm<<<dim3(32, NB), dim3(512), 0, stream>>>(f_t, xm, conv_w, conv_b,
        ck_w, ck_b, ck2_w, ck2_b, ckd4_w, ckd4_b,
        kern_w, kern_b, kern2_w, kern2_b, kernd4_w, kernd4_b, Wb, bt, out);
}

// Round 19
// 405.363 us; speedup vs baseline: 1.2525x; 1.2525x over previous
//
#include <hip/hip_runtime.h>

#define NB   32
#define CIN  256
#define CM   64
#define HWSZ 4096
#define OC   384
#define KTOT 192

typedef __attribute__((ext_vector_type(8))) short bf16x8;
typedef __attribute__((ext_vector_type(4))) float f32x4;

static __device__ __forceinline__ unsigned short f2bf(float v) {
    union { float f; unsigned u; } a; a.f = v;
    unsigned r = a.u + 0x7fffu + ((a.u >> 16) & 1u);
    return (unsigned short)(r >> 16);
}
static __device__ __forceinline__ float bf2f(unsigned short u) {
    union { unsigned u; float f; } a; a.u = ((unsigned)u) << 16;
    return a.f;
}

// ---------- precompute Wb bf16 [384 oc][192 k], bt[384], cwb bf16 [64 ch][256 k], zero xm ----------
__global__ void kw_pre(const float* __restrict__ fuse_w, const float* __restrict__ fuse_b,
                       const float* __restrict__ fc_w, const float* __restrict__ fc_b,
                       const float* __restrict__ conv_w,
                       unsigned short* __restrict__ Wb, float* __restrict__ bt,
                       unsigned short* __restrict__ cwb, float* __restrict__ xm) {
    int k = blockIdx.x;      // 0..192 ; 192 = bias block + cwb convert + xm zero
    int o = threadIdx.x;     // 0..383
    if (k == KTOT) {
        __shared__ float fb[128];
        if (o < 128) fb[o] = fuse_b[o];
        __syncthreads();
        float s = fc_b[o];
        #pragma unroll 4
        for (int q = 0; q < 384; ++q) s += fc_w[o * 384 + q] * fb[q & 127];
        bt[o] = s;
        for (int idx = o; idx < CM * CIN; idx += 384) cwb[idx] = f2bf(conv_w[idx]);
        for (int idx = o; idx < NB * CIN; idx += 384) xm[idx] = 0.f;
        return;
    }
    int i = k >> 6, c = k & 63;
    __shared__ float fw[128];
    if (o < 128) fw[o] = fuse_w[o * 64 + c];
    __syncthreads();
    float s = 0.f;
    #pragma unroll 8
    for (int j = 0; j < 128; ++j) s += fc_w[o * 384 + i * 128 + j] * fw[j];
    Wb[o * KTOT + k] = f2bf(s);
}

// ---------- k3: f_t[n][pix][64] = relu(conv_w @ x + b) via MFMA; also accumulates channel sums ----------
// grid (16 ptiles, 32 n), block 256 (4 waves). Tile: 256 pix (M) x 64 ch (N), K=256.
// Mean fused: per-wave shuffle partial sums -> LDS atomics -> one global atomic per cin per block.
// XCD swizzle: XCD j handles n in [4j,4j+4) (matches k45's mapping for cross-kernel f_t L2 reuse).
// x loads NON-TEMPORAL (read-once stream) -- measured R13: NT package = -12.5us vs non-NT baseline.
__global__ void __launch_bounds__(256) k3_fconv(const float* __restrict__ x,
                                                const unsigned short* __restrict__ cwb,
                                                const float* __restrict__ conv_b,
                                                unsigned short* __restrict__ f_t,
                                                float* __restrict__ xm) {
    __shared__ unsigned short Ab[256 * 40];   // x-tile [pix][32k + 8 pad]
    __shared__ unsigned short Bb[64 * 264];   // cwb [ch][256k + 8 pad]
    __shared__ float sm[CIN];                 // per-block channel sums
    int orig = blockIdx.y * 16 + blockIdx.x;          // 512 blocks, 512%8==0 -> bijective swizzle
    int swz = (orig & 7) * 64 + (orig >> 3);
    int pt = swz & 15, n = swz >> 4;
    int p0 = pt * 256;
    int t = threadIdx.x;
    int lane = t & 63;
    int wv = t >> 6;
    int q = lane >> 4, m16 = lane & 15;

    sm[t] = 0.f;   // 256 threads == CIN

    #pragma unroll
    for (int i = 0; i < 8; ++i) {
        int id = t + i * 256;
        int row = id >> 5, seg = id & 31;
        bf16x8 v = *(const bf16x8*)(cwb + row * CIN + seg * 8);
        *(bf16x8*)(&Bb[row * 264 + seg * 8]) = v;
    }

    f32x4 acc[4][4];
    #pragma unroll
    for (int mt = 0; mt < 4; ++mt)
        #pragma unroll
        for (int nt = 0; nt < 4; ++nt)
            #pragma unroll
            for (int r = 0; r < 4; ++r) acc[mt][nt][r] = 0.f;

    const float* xn = x + (size_t)n * CIN * HWSZ;

    for (int kc = 0; kc < 8; ++kc) {
        __syncthreads();
        #pragma unroll
        for (int i = 0; i < 2; ++i) {
            int id = t + i * 256;
            int kq = id & 7, pg = id >> 3;       // kq: 4-cin group, pg: 4-pixel group
            int cin0 = kc * 32 + kq * 4;
            const float* xp = xn + (size_t)cin0 * HWSZ + p0 + pg * 4;
            f32x4 r0 = __builtin_nontemporal_load((const f32x4*)(xp));
            f32x4 r1 = __builtin_nontemporal_load((const f32x4*)(xp + HWSZ));
            f32x4 r2 = __builtin_nontemporal_load((const f32x4*)(xp + 2 * HWSZ));
            f32x4 r3 = __builtin_nontemporal_load((const f32x4*)(xp + 3 * HWSZ));
            uint2 w;
            w.x = (unsigned)f2bf(r0.x) | ((unsigned)f2bf(r1.x) << 16);
            w.y = (unsigned)f2bf(r2.x) | ((unsigned)f2bf(r3.x) << 16);
            *(uint2*)(&Ab[(pg * 4 + 0) * 40 + kq * 4]) = w;
            w.x = (unsigned)f2bf(r0.y) | ((unsigned)f2bf(r1.y) << 16);
            w.y = (unsigned)f2bf(r2.y) | ((unsigned)f2bf(r3.y) << 16);
            *(uint2*)(&Ab[(pg * 4 + 1) * 40 + kq * 4]) = w;
            w.x = (unsigned)f2bf(r0.z) | ((unsigned)f2bf(r1.z) << 16);
            w.y = (unsigned)f2bf(r2.z) | ((unsigned)f2bf(r3.z) << 16);
            *(uint2*)(&Ab[(pg * 4 + 2) * 40 + kq * 4]) = w;
            w.x = (unsigned)f2bf(r0.w) | ((unsigned)f2bf(r1.w) << 16);
            w.y = (unsigned)f2bf(r2.w) | ((unsigned)f2bf(r3.w) << 16);
            *(uint2*)(&Ab[(pg * 4 + 3) * 40 + kq * 4]) = w;
            // fused mean: per-lane pixel sums for 4 cins, xor-reduce over pg bits, LDS atomic per lane<8
            float s0 = r0.x + r0.y + r0.z + r0.w;
            float s1 = r1.x + r1.y + r1.z + r1.w;
            float s2 = r2.x + r2.y + r2.z + r2.w;
            float s3 = r3.x + r3.y + r3.z + r3.w;
            #pragma unroll
            for (int off = 8; off < 64; off <<= 1) {
                s0 += __shfl_xor(s0, off);
                s1 += __shfl_xor(s1, off);
                s2 += __shfl_xor(s2, off);
                s3 += __shfl_xor(s3, off);
            }
            if (lane < 8) {
                float* sp = &sm[kc * 32 + lane * 4];
                atomicAdd(sp + 0, s0);
                atomicAdd(sp + 1, s1);
                atomicAdd(sp + 2, s2);
                atomicAdd(sp + 3, s3);
            }
        }
        __syncthreads();
        bf16x8 af[4], bfr[4];
        #pragma unroll
        for (int mt = 0; mt < 4; ++mt)
            af[mt] = *(const bf16x8*)(&Ab[(wv * 64 + mt * 16 + m16) * 40 + q * 8]);
        #pragma unroll
        for (int nt = 0; nt < 4; ++nt)
            bfr[nt] = *(const bf16x8*)(&Bb[(nt * 16 + m16) * 264 + kc * 32 + q * 8]);
        #pragma unroll
        for (int mt = 0; mt < 4; ++mt)
            #pragma unroll
            for (int nt = 0; nt < 4; ++nt)
                acc[mt][nt] = __builtin_amdgcn_mfma_f32_16x16x32_bf16(af[mt], bfr[nt], acc[mt][nt], 0, 0, 0);
    }

    // per-block channel sums -> one global atomic per cin (last in-loop barrier guarantees sm complete)
    atomicAdd(xm + n * CIN + t, sm[t]);

    unsigned short* fo = f_t + (size_t)n * HWSZ * CM;
    #pragma unroll
    for (int nt = 0; nt < 4; ++nt) {
        int ch = nt * 16 + m16;
        float b = conv_b[ch];
        #pragma unroll
        for (int mt = 0; mt < 4; ++mt) {
            int pixb = p0 + wv * 64 + mt * 16 + q * 4;
            #pragma unroll
            for (int r = 0; r < 4; ++r) {
                float v = fmaxf(acc[mt][nt][r] + b, 0.f);
                fo[(size_t)(pixb + r) * CM + ch] = f2bf(v);
            }
        }
    }
}

// ---------- k45: g+taps inline (k2 FUSED) -> depthwise (5x5 d1, 3x3 d2, 3x3 d4) -> MFMA GEMM ----------
// grid (32 tiles, 32 n), block 512 (8 waves). Tile = 4 rows x 32 cols of pixels (full 128B out lines).
// [R16 post-mortem: direct-from-L2 depthwise REGRESSED +100us (MfmaUtil 3.9%, VALU 27%, latency-bound:
//  528 global_load_ushort/thread at ~200cy L2 latency; FETCH=9MB proved L2 swizzle works, but LDS
//  staging's 8x VMEM amortization + ~6cy LDS reads is structurally better. REVERTED to R15 form.]
// [R7: 2x32 retile REGRESSED +11us. R13: NT loads/stores -12.5us, kept. R15: k2 fusion flat, kept.]
// Prologue: wave0 computes g[64] = relu(conv_b + dot(xm,conv_w)*2^-12) into LDS; all threads build
// their 43x2 taps in registers with the exact k2 expressions (no karr_t roundtrip).
// Phase 1: halo'd f tile (fl, 12x40) -> depthwise (d2 taps reuse d1 window reads) -> ot[128 pix][192k].
// Phase 2: 3 x (stage Wb 128-oc chunk into fl region; 128oc x 128pix MFMA; store out NON-TEMPORAL).
// XCD swizzle: XCD j handles n in [4j,4j+4) -> per-XCD f_t working set 4 x 524 KB fits 4 MB L2.
__global__ void __launch_bounds__(512, 2) k45_dwgemm(const unsigned short* __restrict__ f_t,
                                                     const float* __restrict__ xm,
                                                     const float* __restrict__ conv_w,
                                                     const float* __restrict__ conv_b,
                                                     const float* ck_w, const float* ck_b,
                                                     const float* ck2_w, const float* ck2_b,
                                                     const float* ckd4_w, const float* ckd4_b,
                                                     const float* kern_w, const float* kern_b,
                                                     const float* kern2_w, const float* kern2_b,
                                                     const float* kernd4_w, const float* kernd4_b,
                                                     const unsigned short* __restrict__ Wb,
                                                     const float* __restrict__ bt,
                                                     float* __restrict__ out) {
    __shared__ unsigned short fl[480 * 72];   // phase1: [12r*40c halo pix][64ch+8pad]; phase2: Wb chunk [128oc][192k+8pad]
    __shared__ unsigned short ot[128 * 200];  // [128 pix][192k + 8 pad]
    __shared__ float bts[128];
    __shared__ float g_sm[CM];                // g = relu(mean @ conv_w^T + b), computed by wave 0
    int orig = blockIdx.y * 32 + blockIdx.x;          // 1024 blocks, 1024%8==0 -> bijective swizzle
    int swz = (orig & 7) * 128 + (orig >> 3);
    int tile = swz & 31, n = swz >> 5;
    int r0 = (tile >> 1) * 4, c0 = (tile & 1) * 32;
    int t = threadIdx.x;
    int lane = t & 63, wv = t >> 6;

    // --- phase 1: stage f halo (480 pix x 64 ch) ---
    const unsigned short* fn = f_t + (size_t)n * HWSZ * CM;
    #pragma unroll
    for (int i = 0; i < 8; ++i) {
        int id = t + i * 512;           // 3840 tasks: 480 pix x 8 ch-groups
        if (id < 3840) {
            int cg = id & 7, pl = id >> 3;
            int lr = pl / 40, lc = pl - lr * 40;
            int gr = r0 + lr - 4, gc = c0 + lc - 4;
            bf16x8 v;
            if ((unsigned)gr < 64u && (unsigned)gc < 64u) {
                v = *(const bf16x8*)(fn + (size_t)(gr * 64 + gc) * CM + cg * 8);
            } else {
                #pragma unroll
                for (int j = 0; j < 8; ++j) v[j] = 0;
            }
            *(bf16x8*)(&fl[pl * 72 + cg * 8]) = v;
        }
    }
    // --- fused k2: wave 0 computes g[c] (xm row wave-uniform -> broadcast; conv_w row per lane) ---
    if (t < CM) {
        const f32x4* xr = (const f32x4*)(xm + (size_t)n * CIN);
        const f32x4* wr = (const f32x4*)(conv_w + t * CIN);
        float a = 0.f;
        #pragma unroll 8
        for (int i = 0; i < CIN / 4; ++i) {
            f32x4 xv = xr[i], wvv = wr[i];
            a = fmaf(xv.x, wvv.x, a); a = fmaf(xv.y, wvv.y, a);
            a = fmaf(xv.z, wvv.z, a); a = fmaf(xv.w, wvv.w, a);
        }
        // 1/4096 is a power of two: scaling after the dot is exact vs k2's scale-then-dot
        g_sm[t] = fmaxf(conv_b[t] + a * (1.0f / 4096.0f), 0.f);
    }
    __syncthreads();

    // --- taps in registers (exact k2 expressions; g from LDS) ---
    int cp = t & 31;       // channel pair: channels 2cp, 2cp+1
    int pg = t >> 5;       // 0..15
    float ge = g_sm[cp * 2], go = g_sm[cp * 2 + 1];
    float2 t1[25], t2[9], t3[9];
    {
        float sw = ck_w[0], sb = ck_b[0];
        #pragma unroll
        for (int i = 0; i < 25; ++i) {
            float kw = kern_w[i], kb = kern_b[i];
            t1[i].x = sw * (ge * kw + kb) + sb;
            t1[i].y = sw * (go * kw + kb) + sb;
        }
        sw = ck2_w[0]; sb = ck2_b[0];
        #pragma unroll
        for (int i = 0; i < 9; ++i) {
            float kw = kern2_w[i], kb = kern2_b[i];
            t2[i].x = sw * (ge * kw + kb) + sb;
            t2[i].y = sw * (go * kw + kb) + sb;
        }
        sw = ckd4_w[0]; sb = ckd4_b[0];
        #pragma unroll
        for (int i = 0; i < 9; ++i) {
            float kw = kernd4_w[i], kb = kernd4_b[i];
            t3[i].x = sw * (ge * kw + kb) + sb;
            t3[i].y = sw * (go * kw + kb) + sb;
        }
    }

    // --- depthwise into ot (d2 is a subset of the d1 5x5 window; d4 center == d1 center) ---
    for (int pass = 0; pass < 8; ++pass) {
        int pli = pg + pass * 16;           // 0..127
        int row = pli >> 5, col = pli & 31;
        int base = ((row + 4) * 40 + (col + 4)) * 72 + cp * 2;
        float s1e = 0.f, s1o = 0.f, s2e = 0.f, s2o = 0.f, s3e = 0.f, s3o = 0.f;
        #pragma unroll
        for (int ky = 0; ky < 5; ++ky)
            #pragma unroll
            for (int kx = 0; kx < 5; ++kx) {
                unsigned fv = *(const unsigned*)(&fl[base + ((ky - 2) * 40 + (kx - 2)) * 72]);
                float fe = bf2f((unsigned short)(fv & 0xffffu));
                float fo = bf2f((unsigned short)(fv >> 16));
                float2 tp = t1[ky * 5 + kx];
                s1e = fmaf(tp.x, fe, s1e);
                s1o = fmaf(tp.y, fo, s1o);
                if (((ky & 1) | (kx & 1)) == 0) {       // (ky-2,kx-2) in {-2,0,2}^2 -> d2 tap
                    float2 tq = t2[(ky >> 1) * 3 + (kx >> 1)];
                    s2e = fmaf(tq.x, fe, s2e);
                    s2o = fmaf(tq.y, fo, s2o);
                }
                if (ky == 2 && kx == 2) {               // d4 center tap
                    float2 tq = t3[4];
                    s3e = fmaf(tq.x, fe, s3e);
                    s3o = fmaf(tq.y, fo, s3o);
                }
            }
        #pragma unroll
        for (int ky = 0; ky < 3; ++ky)
            #pragma unroll
            for (int kx = 0; kx < 3; ++kx) {
                if (ky == 1 && kx == 1) continue;       // center already done
                unsigned fv = *(const unsigned*)(&fl[base + ((ky * 4 - 4) * 40 + (kx * 4 - 4)) * 72]);
                float2 tp = t3[ky * 3 + kx];
                s3e = fmaf(tp.x, bf2f((unsigned short)(fv & 0xffffu)), s3e);
                s3o = fmaf(tp.y, bf2f((unsigned short)(fv >> 16)), s3o);
            }
        unsigned short* ob = &ot[pli * 200];
        *(unsigned*)(ob + cp * 2)       = (unsigned)f2bf(s1e) | ((unsigned)f2bf(s1o) << 16);
        *(unsigned*)(ob + 64 + cp * 2)  = (unsigned)f2bf(s2e) | ((unsigned)f2bf(s2o) << 16);
        *(unsigned*)(ob + 128 + cp * 2) = (unsigned)f2bf(s3e) | ((unsigned)f2bf(s3o) << 16);
    }

    // --- phase 2: GEMM 384oc x 128pix, K=192 ---
    unsigned short* wbs = fl;   // reuse (51.2 KB <= 69.1 KB)
    int wrow = t >> 2, wqk = t & 3;
    int wm = wv & 3, wn = wv >> 2;
    int q = lane >> 4, m16 = lane & 15;
    float* outn0 = out + (size_t)n * OC * HWSZ;
    for (int ocg = 0; ocg < 3; ++ocg) {
        __syncthreads();
        if (t < 128) bts[t] = bt[ocg * 128 + t];
        #pragma unroll
        for (int j = 0; j < 6; ++j) {
            bf16x8 v = *(const bf16x8*)(Wb + (size_t)(ocg * 128 + wrow) * KTOT + wqk * 48 + j * 8);
            *(bf16x8*)(&wbs[wrow * 200 + wqk * 48 + j * 8]) = v;
        }
        __syncthreads();
        f32x4 acc[2][4];
        #pragma unroll
        for (int mt = 0; mt < 2; ++mt)
            #pragma unroll
            for (int nt = 0; nt < 4; ++nt)
                #pragma unroll
                for (int r = 0; r < 4; ++r) acc[mt][nt][r] = 0.f;
        #pragma unroll
        for (int ks = 0; ks < 6; ++ks) {
            bf16x8 af[2], bfr[4];
            #pragma unroll
            for (int mt = 0; mt < 2; ++mt)
                af[mt] = *(const bf16x8*)(&wbs[(wm * 32 + mt * 16 + m16) * 200 + ks * 32 + q * 8]);
            #pragma unroll
            for (int nt = 0; nt < 4; ++nt)
                bfr[nt] = *(const bf16x8*)(&ot[(wn * 64 + nt * 16 + m16) * 200 + ks * 32 + q * 8]);
            #pragma unroll
            for (int mt = 0; mt < 2; ++mt)
                #pragma unroll
                for (int nt = 0; nt < 4; ++nt)
                    acc[mt][nt] = __builtin_amdgcn_mfma_f32_16x16x32_bf16(af[mt], bfr[nt], acc[mt][nt], 0, 0, 0);
        }
        float* outn = outn0 + (size_t)(ocg * 128) * HWSZ;
        #pragma unroll
        for (int mt = 0; mt < 2; ++mt) {
            #pragma unroll
            for (int r = 0; r < 4; ++r) {
                int ocl = wm * 32 + mt * 16 + q * 4 + r;
                float b = bts[ocl];
                #pragma unroll
                for (int nt = 0; nt < 4; ++nt) {
                    int pl = wn * 64 + nt * 16 + m16;
                    int pr = pl >> 5, pc = pl & 31;
                    __builtin_nontemporal_store(acc[mt][nt][r] + b,
                        &outn[(size_t)ocl * HWSZ + (r0 + pr) * 64 + c0 + pc]);
                }
            }
        }
    }
}

extern "C" void kernel_launch(void* const* d_in, const int* in_sizes, int n_in,
                              void* d_out, int out_size, void* d_ws, size_t ws_size,
                              hipStream_t stream) {
    const float* x       = (const float*)d_in[0];
    const float* conv_w  = (const float*)d_in[1];
    const float* conv_b  = (const float*)d_in[2];
    const float* ck_w    = (const float*)d_in[3];
    const float* ck_b    = (const float*)d_in[4];
    const float* ck2_w   = (const float*)d_in[5];
    const float* ck2_b   = (const float*)d_in[6];
    const float* ckd4_w  = (const float*)d_in[7];
    const float* ckd4_b  = (const float*)d_in[8];
    const float* kern_w  = (const float*)d_in[9];
    const float* kern_b  = (const float*)d_in[10];
    const float* kern2_w = (const float*)d_in[11];
    const float* kern2_b = (const float*)d_in[12];
    const float* kernd4_w= (const float*)d_in[13];
    const float* kernd4_b= (const float*)d_in[14];
    const float* fuse_w  = (const float*)d_in[15];
    const float* fuse_b  = (const float*)d_in[16];
    const float* fc_w    = (const float*)d_in[17];
    const float* fc_b    = (const float*)d_in[18];
    float* out = (float*)d_out;

    char* ws = (char*)d_ws;
    float* xm             = (float*)(ws + 0);                  // 32 KB (sums, zeroed by kw_pre)
    float* bt             = (float*)(ws + 385024);             // 1,536 B
    unsigned short* Wb    = (unsigned short*)(ws + 386560);    // 147,456 B
    unsigned short* cwb   = (unsigned short*)(ws + 534016);    // 32,768 B
    unsigned short* f_t   = (unsigned short*)(ws + 566784);    // 16.78 MB -> ends ~17.3 MB

    kw_pre<<<dim3(193), dim3(384), 0, stream>>>(fuse_w, fuse_b, fc_w, fc_b, conv_w, Wb, bt, cwb, xm);
    k3_fconv<<<dim3(16, NB), dim3(256), 0, stream>>>(x, cwb, conv_b, f_t, xm);
    k45_dwgemm<<<dim3(32, NB), dim3(512), 0, stream>>>(f_t, xm, conv_w, conv_b,
        ck_w, ck_b, ck2_w, ck2_b, ckd4_w, ckd4_b,
        kern_w, kern_b, kern2_w, kern2_b, kernd4_w, kernd4_b, Wb, bt, out);
}